// Round 5
// baseline (83.463 us; speedup 1.0000x reference)
//
#include <hip/hip_runtime.h>
#include <hip/hip_fp16.h>

// GAT: B=2, N=4096, F=512, H=8, d=o=64, alpha=0.2
// out[b,n,h*64+c] = elu( sum_m softmax_m(lrelu(f[n]+g[m])) * Wh[m,c] )
// Factorized scores p = max(Ef[n]*Eg[m], Ff[n]*Fg[m]) (all in (0,1], fp16,
// zero transcendentals in O(N^2)). Denominator via v_dot2_f32_f16.
// k_attn: NO LDS / NO barriers in the main loop. B-fragments read directly
// from L2-resident Wh_t. 8 waves = 4(kg: m-split) x 2(wc: col-split) ->
// zero B-read duplication. kg-partials reduced through LDS once at the end.

#define NB   2
#define NN   4096
#define NH   8
#define ALPHA 0.2f
#define LOG2E 1.4426950408889634f

typedef _Float16 f16x8 __attribute__((ext_vector_type(8)));
typedef _Float16 f16x2 __attribute__((ext_vector_type(2)));
typedef float    f32x4 __attribute__((ext_vector_type(4)));

__device__ __forceinline__ float dot2acc(f16x2 a, f16x2 b, float c) {
#if __has_builtin(__builtin_amdgcn_fdot2)
    return __builtin_amdgcn_fdot2(a, b, c, false);
#else
    return c + (float)a[0] * (float)b[0] + (float)a[1] * (float)b[1];
#endif
}

// ---------------------------------------------------------------------------
// Kernel 1: per (b,h), 64-row tile: Wh = h_tile @ W[h]  (fp32 vector GEMM)
// Inner loop: both operands via ds_read_b128 (4-k steps). Outputs:
// Wh_t fp16 [bh][c][n], f'=(Wh.a1)*log2e, g'=(Wh.a2)*log2e.
// ---------------------------------------------------------------------------
__global__ __launch_bounds__(256) void k_wh(
    const float* __restrict__ hsrc, const float* __restrict__ W,
    const float* __restrict__ a,
    _Float16* __restrict__ Wh_t, float* __restrict__ fb, float* __restrict__ gb)
{
    const int bid  = blockIdx.x;
    const int tile = bid & 63;
    const int bh   = bid >> 6;
    const int hh   = bh & 7;
    const int b    = bh >> 3;
    const int n0   = tile * 64;
    const int t    = threadIdx.x;

    __shared__ float Wl[64 * 68];   // [k][c] pad 68 (272B rows, 16B aligned)
    __shared__ float ht[64 * 68];   // [r][k] pad 68; reused as fp16 wt[c][64]
    __shared__ float red[2 * 64 * 16];

    {
        const float* Wg = W + hh * 4096;
        #pragma unroll
        for (int p = 0; p < 4; p++) {
            int idx = (t + p * 256) * 4;
            float4 v = *(const float4*)(Wg + idx);
            int k = idx >> 6, c = idx & 63;
            *(float4*)(&Wl[k * 68 + c]) = v;
        }
    }
    {
        #pragma unroll
        for (int p = 0; p < 4; p++) {
            int idx = t + p * 256;
            int r = idx >> 4, kq = (idx & 15) * 4;
            float4 v = *(const float4*)(hsrc + ((size_t)(b * NN + n0 + r)) * 512 + hh * 64 + kq);
            *(float4*)(&ht[r * 68 + kq]) = v;
        }
    }
    __syncthreads();

    const int rq = t >> 4, cq = t & 15;
    float acc[4][4] = {};
    for (int k4 = 0; k4 < 64; k4 += 4) {
        float4 hv[4], wv[4];
        #pragma unroll
        for (int i = 0; i < 4; i++) hv[i] = *(const float4*)(&ht[(rq * 4 + i) * 68 + k4]);
        #pragma unroll
        for (int kk = 0; kk < 4; kk++) wv[kk] = *(const float4*)(&Wl[(k4 + kk) * 68 + cq * 4]);
        #pragma unroll
        for (int i = 0; i < 4; i++) {
            const float* hp = (const float*)&hv[i];
            #pragma unroll
            for (int kk = 0; kk < 4; kk++) {
                const float* wp = (const float*)&wv[kk];
                #pragma unroll
                for (int j = 0; j < 4; j++)
                    acc[i][j] = fmaf(hp[kk], wp[j], acc[i][j]);
            }
        }
    }

    float a1v[4], a2v[4];
    {
        const float* ag = a + hh * 128;
        #pragma unroll
        for (int j = 0; j < 4; j++) { a1v[j] = ag[cq * 4 + j]; a2v[j] = ag[64 + cq * 4 + j]; }
    }
    __syncthreads();

    _Float16* wt = (_Float16*)ht;    // [c][64 rows]
    #pragma unroll
    for (int i = 0; i < 4; i++) {
        float fp = 0.f, gp = 0.f;
        #pragma unroll
        for (int j = 0; j < 4; j++) {
            fp = fmaf(acc[i][j], a1v[j], fp);
            gp = fmaf(acc[i][j], a2v[j], gp);
        }
        red[0 * 1024 + (rq * 4 + i) * 16 + cq] = fp;
        red[1 * 1024 + (rq * 4 + i) * 16 + cq] = gp;
        #pragma unroll
        for (int j = 0; j < 4; j++)
            wt[(cq * 4 + j) * 64 + rq * 4 + i] = (_Float16)acc[i][j];
    }
    __syncthreads();

    if (t < 128) {
        int which = t >> 6, row = t & 63;
        const float* rr = &red[which * 1024 + row * 16];
        float s = 0.f;
        #pragma unroll
        for (int j = 0; j < 16; j++) s += rr[j];
        s *= LOG2E;
        float* dst = which ? gb : fb;
        dst[(size_t)bh * NN + n0 + row] = s;
    }
    #pragma unroll
    for (int p = 0; p < 2; p++) {
        int idx = t + p * 256;
        int c = idx >> 3, seg = idx & 7;
        float4 v = *(const float4*)(&wt[c * 64 + seg * 8]);
        *(float4*)(Wh_t + (size_t)bh * 64 * NN + (size_t)c * NN + n0 + seg * 8) = v;
    }
}

// ---------------------------------------------------------------------------
// Kernel prep: per bh: G = max g'; Eg = 2^(g-G), Fg = 2^(alpha*(g-G)) fp16.
// Eg/Fg ALIAS the g storage: all g reads into regs before aliased writes.
// ---------------------------------------------------------------------------
__global__ __launch_bounds__(256) void k_prep(const float* __restrict__ gball,
                                              float* __restrict__ G,
                                              char* __restrict__ egfg_base)
{
    int bh = blockIdx.x, t = threadIdx.x;
    const float* g = gball + (size_t)bh * NN;
    float vals[16];
    float m = -1e30f;
    #pragma unroll
    for (int j = 0; j < 16; j++) { vals[j] = g[t + j * 256]; m = fmaxf(m, vals[j]); }
    #pragma unroll
    for (int s = 1; s < 64; s <<= 1) m = fmaxf(m, __shfl_xor(m, s, 64));
    __shared__ float wm[4];
    if ((t & 63) == 0) wm[t >> 6] = m;
    __syncthreads();
    float Gv = fmaxf(fmaxf(wm[0], wm[1]), fmaxf(wm[2], wm[3]));
    if (t == 0) G[bh] = Gv;
    _Float16* Eg = (_Float16*)(egfg_base + (size_t)bh * 16384);
    _Float16* Fg = Eg + NN;
    #pragma unroll
    for (int j = 0; j < 16; j++) {
        int i = t + j * 256;
        float d = vals[j] - Gv;
        Eg[i] = (_Float16)exp2f(d);
        Fg[i] = (_Float16)exp2f(ALPHA * d);
    }
}

// ---------------------------------------------------------------------------
// Kernel 2: attention, barrier-free main loop.
// 512 blocks x 512 thr. Block: 128 rows x 64 cols x all m. Wave w:
// kg=w>>1 (m-range kg*1024..+1024), wc=w&1 (cols wc*32..+32).
// Per wave: acc[8 rg][2 ct]; per superstep (64 m): 4 global b128 B-frag
// loads (L2-hit) + 4 eg/fg loads + 16 af-builds + 32 MFMA. No LDS, no
// __syncthreads until the one-time kg-reduction epilogue.
// ---------------------------------------------------------------------------
__global__ __launch_bounds__(512, 4) void k_attn(
    const _Float16* __restrict__ Wh_t, const float* __restrict__ fb,
    const float* __restrict__ G, const char* __restrict__ egfg_base,
    float* __restrict__ out)
{
    // XCD-bijective swizzle: 512 = 8 XCD x 64; XCD x owns 2 full bh slices.
    const int orig  = blockIdx.x;
    const int bid   = (orig & 7) * 64 + (orig >> 3);
    const int ntile = bid & 31;
    const int bh    = bid >> 5;
    const int hh    = bh & 7;
    const int b     = bh >> 3;
    const int n0    = ntile * 128;
    const int t     = threadIdx.x;
    const int w     = t >> 6;
    const int l     = t & 63;
    const int kg    = w >> 1;        // 0..3 m-split
    const int wc    = w & 1;         // 0..1 col-split
    const int lr    = l & 15;
    const int lg    = l >> 4;

    const _Float16* Wp  = Wh_t + (size_t)bh * 64 * NN;
    const _Float16* Egp = (const _Float16*)(egfg_base + (size_t)bh * 16384);
    const float     Gv  = G[bh];

    // per-row factors for all 8 row-groups (one of Ef,Ff is exactly 1)
    f16x2 ef2[8], ff2[8];
    #pragma unroll
    for (int rg = 0; rg < 8; rg++) {
        int rn = n0 + rg * 16 + lr;
        float s  = fb[(size_t)bh * NN + rn] + Gv;
        float t1 = (1.f - ALPHA) * s;
        _Float16 e = (_Float16)exp2f(fminf(t1, 0.f));
        _Float16 f = (_Float16)exp2f(fminf(-t1, 0.f));
        ef2[rg] = (f16x2){e, e};
        ff2[rg] = (f16x2){f, f};
    }
    const f16x2 one2 = (f16x2){(_Float16)1.0f, (_Float16)1.0f};

    f32x4 acc[8][2];
    #pragma unroll
    for (int rg = 0; rg < 8; rg++) {
        acc[rg][0] = (f32x4){0.f, 0.f, 0.f, 0.f};
        acc[rg][1] = (f32x4){0.f, 0.f, 0.f, 0.f};
    }
    float dsum[8] = {0.f, 0.f, 0.f, 0.f, 0.f, 0.f, 0.f, 0.f};

    // fragment base pointers (include lane offsets)
    const _Float16* bp0 = Wp + (size_t)(wc * 32 + lr) * NN + kg * 1024 + lg * 8;
    const _Float16* bp1 = bp0 + (size_t)16 * NN;
    const _Float16* ep  = Egp + kg * 1024 + lg * 8;
    const _Float16* epf = ep + NN;

    #define KH_BLOCK(BOFF)                                                          \
        {                                                                            \
            f16x8 b0  = *(const f16x8*)(bp0 + mo + (BOFF));                          \
            f16x8 b1  = *(const f16x8*)(bp1 + mo + (BOFF));                          \
            f16x8 eg8 = *(const f16x8*)(ep  + mo + (BOFF));                          \
            f16x8 fg8 = *(const f16x8*)(epf + mo + (BOFF));                          \
            _Pragma("unroll")                                                        \
            for (int rg = 0; rg < 8; rg++) {                                         \
                f16x8 af; float ds = dsum[rg];                                       \
                _Pragma("unroll")                                                    \
                for (int d = 0; d < 4; d++) {                                        \
                    f16x2 e2 = ((const f16x2*)&eg8)[d];                              \
                    f16x2 f2 = ((const f16x2*)&fg8)[d];                              \
                    f16x2 p2 = __builtin_elementwise_max(e2 * ef2[rg], f2 * ff2[rg]);\
                    ((f16x2*)&af)[d] = p2;                                           \
                    ds = dot2acc(p2, one2, ds);                                      \
                }                                                                    \
                dsum[rg] = ds;                                                       \
                acc[rg][0] = __builtin_amdgcn_mfma_f32_16x16x32_f16(                 \
                    af, b0, acc[rg][0], 0, 0, 0);                                    \
                acc[rg][1] = __builtin_amdgcn_mfma_f32_16x16x32_f16(                 \
                    af, b1, acc[rg][1], 0, 0, 0);                                    \
            }                                                                        \
        }

    for (int ss = 0; ss < 16; ss++) {
        const int mo = ss * 64;
        KH_BLOCK(0)
        KH_BLOCK(32)
    }
    #undef KH_BLOCK

    // ---------------- epilogue: kg-reduction (one-time) ----------------
    __shared__ f32x4 __attribute__((aligned(16))) Rw[2][16 * 64];  // 32 KB
    __shared__ float dnP[512];
    __shared__ float dnS[128];

    // per-row denominator partials (reduce lg groups in-wave)
    #pragma unroll
    for (int rg = 0; rg < 8; rg++) {
        float d = dsum[rg];
        d += __shfl_xor(d, 16, 64);
        d += __shfl_xor(d, 32, 64);
        if (lg == 0 && wc == 0) dnP[kg * 128 + rg * 16 + lr] = d;
    }

    #define WRITE_R()                                                            \
        { _Pragma("unroll") for (int rg = 0; rg < 8; rg++)                       \
          _Pragma("unroll") for (int ct = 0; ct < 2; ct++)                       \
            Rw[wc][(rg * 2 + ct) * 64 + l] = acc[rg][ct]; }
    #define ADD_R()                                                              \
        { _Pragma("unroll") for (int rg = 0; rg < 8; rg++)                       \
          _Pragma("unroll") for (int ct = 0; ct < 2; ct++)                       \
            acc[rg][ct] += Rw[wc][(rg * 2 + ct) * 64 + l]; }

    if (kg == 1) WRITE_R();
    __syncthreads();
    if (t < 128) dnS[t] = dnP[t] + dnP[128 + t] + dnP[256 + t] + dnP[384 + t];
    if (kg == 0) ADD_R();
    __syncthreads();
    if (kg == 2) WRITE_R();
    __syncthreads();
    if (kg == 0) ADD_R();
    __syncthreads();
    if (kg == 3) WRITE_R();
    __syncthreads();

    if (kg == 0) {
        ADD_R();
        float* outp = out + ((size_t)(b * NN + n0)) * 512 + hh * 64 + wc * 32;
        #pragma unroll
        for (int rg = 0; rg < 8; rg++)
            #pragma unroll
            for (int reg = 0; reg < 4; reg++) {
                int row = rg * 16 + lg * 4 + reg;
                float rinv = 1.0f / dnS[row];
                #pragma unroll
                for (int ct = 0; ct < 2; ct++) {
                    float v = acc[rg][ct][reg] * rinv;
                    v = v > 0.f ? v : (exp2f(v * LOG2E) - 1.f);   // elu
                    outp[(size_t)row * 512 + ct * 16 + lr] = v;
                }
            }
    }
    #undef WRITE_R
    #undef ADD_R
}

// ---------------------------------------------------------------------------
extern "C" void kernel_launch(void* const* d_in, const int* in_sizes, int n_in,
                              void* d_out, int out_size, void* d_ws, size_t ws_size,
                              hipStream_t stream)
{
    const float* hsrc = (const float*)d_in[0];
    const float* W    = (const float*)d_in[1];
    const float* a    = (const float*)d_in[2];
    float* outp       = (float*)d_out;

    const size_t WHT_BYTES = (size_t)NB * NH * 64 * NN * sizeof(_Float16); // 8 MB
    const size_t FB_BYTES  = (size_t)NB * NH * NN * sizeof(float);         // 256 KB
    const size_t GB_BYTES  = (size_t)NB * NH * NN * sizeof(float);         // 256 KB
    const size_t NEED = WHT_BYTES + FB_BYTES + GB_BYTES + 64 * sizeof(float);
    if (ws_size < NEED) return;

    char* ws = (char*)d_ws;
    _Float16* Wh_t = (_Float16*)ws;
    float*    fbuf = (float*)(ws + WHT_BYTES);
    char*     gbase = ws + WHT_BYTES + FB_BYTES;   // g' f32 -> Eg|Fg fp16 (aliased)
    float*    Gmax = (float*)(ws + WHT_BYTES + FB_BYTES + GB_BYTES);

    k_wh  <<<dim3(NB * NH * (NN / 64)),  dim3(256), 0, stream>>>(hsrc, W, a, Wh_t, fbuf, (float*)gbase);
    k_prep<<<dim3(NB * NH),              dim3(256), 0, stream>>>((const float*)gbase, Gmax, gbase);
    k_attn<<<dim3(NB * NH * (NN / 128)), dim3(512), 0, stream>>>(Wh_t, fbuf, Gmax, gbase, outp);
}